// Round 1
// 690.147 us; speedup vs baseline: 1.1520x; 1.1520x over previous
//
#include <hip/hip_runtime.h>
#include <math.h>

// Problem constants (fixed by setup_inputs)
#define BATCH 16
#define TMAX  256
#define UU    64      // label length U
#define U1    65      // U+1
#define V1    513     // vocab+blank
#define BLANKI 512
#define NEG_INF (-INFINITY)

// Workspace layout (floats):
//   [0..16)                losses per sequence
//   blank slabs: per b, BLK_ROWS x U1, with BLK_PAD leading pad rows
//   lab   slabs: per b, LAB_ROWS x UU, with LAB_PAD leading pad rows
// Pads (and any overrun into later ws regions) absorb out-of-range prefetch
// reads in alpha. Harness poison is finite; every out-of-range operand is
// annihilated by a -inf term or masked to -inf before use (verified by the
// previously-passing kernel using the same invariant).
#define BLK_PAD  64
#define LAB_PAD  64
#define BLK_ROWS 384   // rows -64 .. 319
#define LAB_ROWS 392   // rows -64 .. 327
#define BLK_SLAB (BLK_ROWS * U1)
#define LAB_SLAB (LAB_ROWS * UU)
#define LOSS_OFF 0
#define BLK_OFF  16
#define LAB_OFF  (BLK_OFF + BATCH * BLK_SLAB)

__device__ __forceinline__ float lae(float x, float y) {
    // fast logaddexp; NaN only when both inputs are -inf (always masked after)
    float m = fmaxf(x, y);
    float z = fminf(x, y);
    return m + __logf(1.0f + __expf(z - m));
}

// Kernel 1: one wave per (b,t,u) cell. logsumexp over 513 logits,
// emit blank_lp and lab_lp into padded slabs. Dead cells (t >= T_len or
// u > U_len) exit before any load.
// Loads: row base dword index is wave*513, so base+(wave&1) is 8B-aligned.
//   even rows: dwordx2 over els [0,512), scalar el 512 (blank) on lane 0
//   odd  rows: dwordx2 over els [1,513), scalar el 0 on lane 0
// 4x dwordx2 per lane (512 B per wave-instr) halves VMEM instruction count
// vs 8x dword. Tail stores issue from two lanes in parallel.
__global__ __launch_bounds__(1024) void lse_kernel(const float* __restrict__ logits,
                                                   const int* __restrict__ y,
                                                   const int* __restrict__ logit_lens,
                                                   const int* __restrict__ y_lens,
                                                   float* __restrict__ ws) {
    const int wave = (int)((blockIdx.x * 1024u + threadIdx.x) >> 6);
    const int lane = threadIdx.x & 63;
    const int ncells = BATCH * TMAX * U1;
    if (wave >= ncells) return;

    const int u  = wave % U1;
    const int bt = wave / U1;          // b*TMAX + t
    const int b  = bt / TMAX;
    const int t  = bt - b * TMAX;
    if (t >= logit_lens[b] || u > y_lens[b]) return;   // dead cell: no loads

    const long long base = (long long)wave * V1;
    const int odd = wave & 1;                       // wave-uniform
    const long long vbase = base + odd;             // even dword index -> 8B aligned

    float2 v[4];
    const float2* __restrict__ vp = (const float2*)(logits + vbase);
#pragma unroll
    for (int k = 0; k < 4; ++k) v[k] = vp[lane + (k << 6)];
    // leftover element: blank (512) for even rows, element 0 for odd rows
    const float extra = (lane == 0) ? logits[base + (odd ? 0 : BLANKI)] : NEG_INF;

    float m = extra;
#pragma unroll
    for (int k = 0; k < 4; ++k) m = fmaxf(m, fmaxf(v[k].x, v[k].y));
#pragma unroll
    for (int off = 32; off; off >>= 1) m = fmaxf(m, __shfl_xor(m, off));

    float s = (lane == 0) ? __expf(extra - m) : 0.0f;
#pragma unroll
    for (int k = 0; k < 4; ++k) s += __expf(v[k].x - m) + __expf(v[k].y - m);
#pragma unroll
    for (int off = 32; off; off >>= 1) s += __shfl_xor(s, off);

    const float lse = m + __logf(s);   // all lanes hold it after butterfly

    // blank logit lives in lane0's 'extra' (even rows) or lane63's v[3].y
    // (odd rows: el 1+2*63+1+384 = 512). Store from the owning lane; label
    // store from lane 1 concurrently.
    const float vb_own  = odd ? v[3].y : extra;
    const int  blk_lane = odd ? 63 : 0;
    if (lane == blk_lane) {
        float* blk = ws + BLK_OFF + b * BLK_SLAB + BLK_PAD * U1;
        blk[t * U1 + u] = vb_own - lse;
    }
    if (lane == 1 && u < UU) {
        float* lab = ws + LAB_OFF + b * LAB_SLAB + LAB_PAD * UU;
        const int label = y[b * UU + u];
        lab[t * UU + u] = logits[base + label] - lse;  // row is L1-hot
    }
}

// Kernel 2: diagonal-wavefront alpha, one block (one wave, one CU) per
// sequence. Lane u holds alpha[d-u, u] on anti-diagonal d=t+u; column u=64
// is a lane-uniform register. Operand loads are pure pointer arithmetic into
// padded slabs, software-pipelined DEPTH=8 diagonals ahead so the ~100-200cy
// L1/L2 latency is fully hidden (the old 1-deep prefetch stalled every
// diagonal). Loop is unrolled by 8; since the trip count rounds up past dEnd,
// the result is snapshotted at d==dEnd (overrun substeps read in-ws garbage
// that is masked exactly like the pads).
#define ADEPTH 8
__global__ __launch_bounds__(64) void alpha_kernel(const float* __restrict__ ws,
                                                   const int* __restrict__ logit_lens,
                                                   const int* __restrict__ y_lens,
                                                   float* __restrict__ losses) {
    const int b    = blockIdx.x;
    const int lane = threadIdx.x;

    const float* __restrict__ blk = ws + BLK_OFF + b * BLK_SLAB + BLK_PAD * U1;
    const float* __restrict__ lab = ws + LAB_OFF + b * LAB_SLAB + LAB_PAD * UU;
    const int Tl = logit_lens[b];
    const int Ul = y_lens[b];
    const int dEnd = Tl - 1 + Ul;

    float a   = (lane == 0) ? 0.0f : NEG_INF;  // alpha[0,0] = 0
    float a64 = NEG_INF;
    const int lm1 = (lane == 0) ? 0 : (lane - 1);

    // operand addresses at diagonal d:
    //   blank[d-1-lane, lane], lab[d-lane, lane-1], blank[d-65,64], lab[d-64,63]
    // pointers below sit at d=1; they advance one row per diagonal.
    const float* pb   = blk + (0 - lane) * U1 + lane;
    const float* pl   = lab + (1 - lane) * UU + lm1;
    const float* pb64 = blk + (1 - 65) * U1 + 64;
    const float* pl63 = lab + (1 - 64) * UU + 63;

    // prefetch queues: q*[k] holds operands for diagonal d0+k (d0 = trip*8+1)
    float qb[ADEPTH], ql[ADEPTH], qb64[ADEPTH], ql63[ADEPTH];
#pragma unroll
    for (int k = 0; k < ADEPTH; ++k) {
        qb[k]   = pb[k * U1];
        ql[k]   = pl[k * UU];
        qb64[k] = pb64[k * U1];
        ql63[k] = pl63[k * UU];
    }

    float aSnap = NEG_INF, a64Snap = NEG_INF;
    int dml = 1 - lane;   // d - lane
    int d   = 1;
    const int trips = (dEnd + ADEPTH - 1) / ADEPTH;
    for (int trip = 0; trip < trips; ++trip) {
        // issue next trip's 32 loads up front (8 diagonals ahead of use)
        pb += ADEPTH * U1; pl += ADEPTH * UU; pb64 += ADEPTH * U1; pl63 += ADEPTH * UU;
        float nb[ADEPTH], nl[ADEPTH], nb64[ADEPTH], nl63[ADEPTH];
#pragma unroll
        for (int k = 0; k < ADEPTH; ++k) {
            nb[k]   = pb[k * U1];
            nl[k]   = pl[k * UU];
            nb64[k] = pb64[k * U1];
            nl63[k] = pl63[k * UU];
        }
#pragma unroll
        for (int k = 0; k < ADEPTH; ++k) {
            const float left = __shfl_up(a, 1);     // alpha[d-lane, lane-1]
            const float a63b = __shfl(a, 63);       // alpha[d-64, 63]

            const float up_in   = a + qb[k];
            const float left_in = (lane == 0) ? NEG_INF : (left + ql[k]);
            const float val     = lae(up_in, left_in);
            a = ((unsigned)dml < (unsigned)Tl) ? val : NEG_INF;

            const float v64 = lae(a64 + qb64[k], a63b + ql63[k]);
            a64 = ((unsigned)(d - 64) < (unsigned)Tl) ? v64 : NEG_INF;

            if (d == dEnd) { aSnap = a; a64Snap = a64; }  // capture before overrun
            ++dml; ++d;
        }
#pragma unroll
        for (int k = 0; k < ADEPTH; ++k) {
            qb[k] = nb[k]; ql[k] = nl[k]; qb64[k] = nb64[k]; ql63[k] = nl63[k];
        }
    }

    // ll = alpha[Tl-1, Ul] + blank_lp[Tl-1, Ul]
    const float aU    = (Ul < 64) ? __shfl(aSnap, Ul) : a64Snap;
    const float blast = blk[(Tl - 1) * U1 + Ul];
    if (lane == 0) losses[b] = -(aU + blast);
}

// Kernel 3: mean over the 16 per-sequence losses.
__global__ __launch_bounds__(64) void finalize_kernel(const float* __restrict__ losses,
                                                      float* __restrict__ out) {
    const int lane = threadIdx.x;
    float v = (lane < BATCH) ? losses[lane] : 0.0f;
#pragma unroll
    for (int off = 32; off; off >>= 1) v += __shfl_xor(v, off);
    if (lane == 0) out[0] = v * (1.0f / BATCH);
}

extern "C" void kernel_launch(void* const* d_in, const int* in_sizes, int n_in,
                              void* d_out, int out_size, void* d_ws, size_t ws_size,
                              hipStream_t stream) {
    const float* logits     = (const float*)d_in[0];
    const int*   logit_lens = (const int*)d_in[1];
    const int*   y          = (const int*)d_in[2];
    const int*   y_lens     = (const int*)d_in[3];
    float* out = (float*)d_out;
    float* ws  = (float*)d_ws;

    const int ncells = BATCH * TMAX * U1;                 // 266240 waves
    const int grid = (ncells + 15) / 16;                  // 16 waves/block
    lse_kernel<<<grid, 1024, 0, stream>>>(logits, y, logit_lens, y_lens, ws);
    alpha_kernel<<<BATCH, 64, 0, stream>>>(ws, logit_lens, y_lens, ws + LOSS_OFF);
    finalize_kernel<<<1, 64, 0, stream>>>(ws + LOSS_OFF, out);
}

// Round 2
// 688.989 us; speedup vs baseline: 1.1539x; 1.0017x over previous
//
#include <hip/hip_runtime.h>
#include <math.h>

// Problem constants (fixed by setup_inputs)
#define BATCH 16
#define TMAX  256
#define UU    64      // label length U
#define U1    65      // U+1
#define V1    513     // vocab+blank
#define BLANKI 512
#define NEG_INF (-INFINITY)

// Workspace layout (floats):
//   [0..16)                losses per sequence
//   blank slabs: per b, BLK_ROWS x U1, with BLK_PAD leading pad rows
//   lab   slabs: per b, LAB_ROWS x UU, with LAB_PAD leading pad rows
// Pads (and any overrun into later ws regions) absorb out-of-range prefetch
// reads in alpha. Harness poison is finite; every out-of-range operand is
// annihilated by a -inf term or masked to -inf before use.
#define BLK_PAD  64
#define LAB_PAD  64
#define BLK_ROWS 384   // rows -64 .. 319
#define LAB_ROWS 392   // rows -64 .. 327
#define BLK_SLAB (BLK_ROWS * U1)
#define LAB_SLAB (LAB_ROWS * UU)
#define LOSS_OFF 0
#define BLK_OFF  16
#define LAB_OFF  (BLK_OFF + BATCH * BLK_SLAB)

__device__ __forceinline__ float lae(float x, float y) {
    // fast logaddexp; NaN only when both inputs are -inf (always masked after)
    float m = fmaxf(x, y);
    float z = fminf(x, y);
    return m + __logf(1.0f + __expf(z - m));
}

// Wave-wide logsumexp over 8 float2 per lane plus a lane-private 'extra'
// (NEG_INF on lanes that don't own one; exp(-inf - m) == 0 exactly).
// Operation order matches the round-1 kernel bit-for-bit.
__device__ __forceinline__ float wave_lse_f2(const float2 v[4], float extra) {
    float m = extra;
#pragma unroll
    for (int k = 0; k < 4; ++k) m = fmaxf(m, fmaxf(v[k].x, v[k].y));
#pragma unroll
    for (int off = 32; off; off >>= 1) m = fmaxf(m, __shfl_xor(m, off));

    float s = __expf(extra - m);   // == 0 for lanes with extra == -inf
#pragma unroll
    for (int k = 0; k < 4; ++k) s += __expf(v[k].x - m) + __expf(v[k].y - m);
#pragma unroll
    for (int off = 32; off; off >>= 1) s += __shfl_xor(s, off);

    return m + __logf(s);
}

// Kernel 1: one wave per PAIR of (b,t,u) cells (cells 2w, 2w+1). Pairing
// halves wave count and doubles memory-level parallelism: both cells' loads
// issue before either reduction, so the second cell's ~900-cycle HBM latency
// hides under the first cell's butterfly. Parity is compile-time now:
//   cell A (even dword base, 8B-aligned): float2 over els [0,512), extra=el 512 (blank)
//   cell B (odd base; base+1 aligned):    float2 over els [1,513), extra=el 0,
//                                         blank = lane63 v[3].y (el 512)
// Dead cells load nothing; fully-dead pairs exit before any VMEM.
__global__ __launch_bounds__(1024) void lse_kernel(const float* __restrict__ logits,
                                                   const int* __restrict__ y,
                                                   const int* __restrict__ logit_lens,
                                                   const int* __restrict__ y_lens,
                                                   float* __restrict__ ws) {
    const int wave = (int)((blockIdx.x * 1024u + threadIdx.x) >> 6);
    const int lane = threadIdx.x & 63;
    const int npairs = (BATCH * TMAX * U1) / 2;   // 266240/2 = 133120, exact
    if (wave >= npairs) return;

    const int c0 = wave * 2;       // even
    const int c1 = c0 + 1;         // odd

    const int u0  = c0 % U1;  const int bt0 = c0 / U1;
    const int b0  = bt0 / TMAX; const int t0 = bt0 - b0 * TMAX;
    const int u1v = c1 % U1;  const int bt1 = c1 / U1;
    const int b1  = bt1 / TMAX; const int t1 = bt1 - b1 * TMAX;

    const bool live0 = (t0 < logit_lens[b0]) && (u0  <= y_lens[b0]);
    const bool live1 = (t1 < logit_lens[b1]) && (u1v <= y_lens[b1]);
    if (!live0 && !live1) return;

    const long long base0 = (long long)c0 * V1;   // even dword index
    const long long base1 = base0 + V1;           // odd dword index

    float2 vA[4], vB[4];
    float exA = NEG_INF, exB = NEG_INF;
    float labA = 0.0f,  labB = 0.0f;

    // ---- load phase: issue everything before either reduction ----
    if (live0) {
        const float2* __restrict__ vp = (const float2*)(logits + base0);
#pragma unroll
        for (int k = 0; k < 4; ++k) vA[k] = vp[lane + (k << 6)];
        if (lane == 0) exA = logits[base0 + BLANKI];
        if (lane == 1 && u0 < UU) labA = logits[base0 + y[b0 * UU + u0]];
    }
    if (live1) {
        const float2* __restrict__ vp = (const float2*)(logits + base1 + 1);
#pragma unroll
        for (int k = 0; k < 4; ++k) vB[k] = vp[lane + (k << 6)];
        if (lane == 0) exB = logits[base1];       // element 0
        if (lane == 1 && u1v < UU) labB = logits[base1 + y[b1 * UU + u1v]];
    }

    // ---- reduce + store, cell A ----
    if (live0) {
        const float lse = wave_lse_f2(vA, exA);
        if (lane == 0) {
            float* blkp = ws + BLK_OFF + b0 * BLK_SLAB + BLK_PAD * U1;
            blkp[t0 * U1 + u0] = exA - lse;       // blank lp
        }
        if (lane == 1 && u0 < UU) {
            float* labp = ws + LAB_OFF + b0 * LAB_SLAB + LAB_PAD * UU;
            labp[t0 * UU + u0] = labA - lse;
        }
    }
    // ---- reduce + store, cell B ----
    if (live1) {
        const float lse = wave_lse_f2(vB, exB);
        if (lane == 63) {
            float* blkp = ws + BLK_OFF + b1 * BLK_SLAB + BLK_PAD * U1;
            blkp[t1 * U1 + u1v] = vB[3].y - lse;  // el 1+2*(63+192)+1 == 512 (blank)
        }
        if (lane == 1 && u1v < UU) {
            float* labp = ws + LAB_OFF + b1 * LAB_SLAB + LAB_PAD * UU;
            labp[t1 * UU + u1v] = labB - lse;
        }
    }
}

// Kernel 2: diagonal-wavefront alpha, one block (one wave, one CU) per
// sequence. Lane u holds alpha[d-u, u] on anti-diagonal d=t+u; column u=64
// is a lane-uniform register. Operand loads are pure pointer arithmetic into
// padded slabs, software-pipelined DEPTH=8 diagonals ahead so L2/L3 latency
// is fully hidden. Loop is unrolled by 8; since the trip count rounds up past
// dEnd, the result is snapshotted at d==dEnd (overrun substeps read in-ws
// garbage that is masked exactly like the pads).
#define ADEPTH 8
__global__ __launch_bounds__(64) void alpha_kernel(const float* __restrict__ ws,
                                                   const int* __restrict__ logit_lens,
                                                   const int* __restrict__ y_lens,
                                                   float* __restrict__ losses) {
    const int b    = blockIdx.x;
    const int lane = threadIdx.x;

    const float* __restrict__ blk = ws + BLK_OFF + b * BLK_SLAB + BLK_PAD * U1;
    const float* __restrict__ lab = ws + LAB_OFF + b * LAB_SLAB + LAB_PAD * UU;
    const int Tl = logit_lens[b];
    const int Ul = y_lens[b];
    const int dEnd = Tl - 1 + Ul;

    float a   = (lane == 0) ? 0.0f : NEG_INF;  // alpha[0,0] = 0
    float a64 = NEG_INF;
    const int lm1 = (lane == 0) ? 0 : (lane - 1);

    // operand addresses at diagonal d:
    //   blank[d-1-lane, lane], lab[d-lane, lane-1], blank[d-65,64], lab[d-64,63]
    const float* pb   = blk + (0 - lane) * U1 + lane;
    const float* pl   = lab + (1 - lane) * UU + lm1;
    const float* pb64 = blk + (1 - 65) * U1 + 64;
    const float* pl63 = lab + (1 - 64) * UU + 63;

    // prefetch queues: q*[k] holds operands for diagonal d0+k
    float qb[ADEPTH], ql[ADEPTH], qb64[ADEPTH], ql63[ADEPTH];
#pragma unroll
    for (int k = 0; k < ADEPTH; ++k) {
        qb[k]   = pb[k * U1];
        ql[k]   = pl[k * UU];
        qb64[k] = pb64[k * U1];
        ql63[k] = pl63[k * UU];
    }

    float aSnap = NEG_INF, a64Snap = NEG_INF;
    int dml = 1 - lane;   // d - lane
    int d   = 1;
    const int trips = (dEnd + ADEPTH - 1) / ADEPTH;
    for (int trip = 0; trip < trips; ++trip) {
        // issue next trip's 32 loads up front (8 diagonals ahead of use)
        pb += ADEPTH * U1; pl += ADEPTH * UU; pb64 += ADEPTH * U1; pl63 += ADEPTH * UU;
        float nb[ADEPTH], nl[ADEPTH], nb64[ADEPTH], nl63[ADEPTH];
#pragma unroll
        for (int k = 0; k < ADEPTH; ++k) {
            nb[k]   = pb[k * U1];
            nl[k]   = pl[k * UU];
            nb64[k] = pb64[k * U1];
            nl63[k] = pl63[k * UU];
        }
#pragma unroll
        for (int k = 0; k < ADEPTH; ++k) {
            const float left = __shfl_up(a, 1);     // alpha[d-lane, lane-1]
            const float a63b = __shfl(a, 63);       // alpha[d-64, 63]

            const float up_in   = a + qb[k];
            const float left_in = (lane == 0) ? NEG_INF : (left + ql[k]);
            const float val     = lae(up_in, left_in);
            a = ((unsigned)dml < (unsigned)Tl) ? val : NEG_INF;

            const float v64 = lae(a64 + qb64[k], a63b + ql63[k]);
            a64 = ((unsigned)(d - 64) < (unsigned)Tl) ? v64 : NEG_INF;

            if (d == dEnd) { aSnap = a; a64Snap = a64; }  // capture before overrun
            ++dml; ++d;
        }
#pragma unroll
        for (int k = 0; k < ADEPTH; ++k) {
            qb[k] = nb[k]; ql[k] = nl[k]; qb64[k] = nb64[k]; ql63[k] = nl63[k];
        }
    }

    // ll = alpha[Tl-1, Ul] + blank_lp[Tl-1, Ul]
    const float aU    = (Ul < 64) ? __shfl(aSnap, Ul) : a64Snap;
    const float blast = blk[(Tl - 1) * U1 + Ul];
    if (lane == 0) losses[b] = -(aU + blast);
}

// Kernel 3: mean over the 16 per-sequence losses.
__global__ __launch_bounds__(64) void finalize_kernel(const float* __restrict__ losses,
                                                      float* __restrict__ out) {
    const int lane = threadIdx.x;
    float v = (lane < BATCH) ? losses[lane] : 0.0f;
#pragma unroll
    for (int off = 32; off; off >>= 1) v += __shfl_xor(v, off);
    if (lane == 0) out[0] = v * (1.0f / BATCH);
}

extern "C" void kernel_launch(void* const* d_in, const int* in_sizes, int n_in,
                              void* d_out, int out_size, void* d_ws, size_t ws_size,
                              hipStream_t stream) {
    const float* logits     = (const float*)d_in[0];
    const int*   logit_lens = (const int*)d_in[1];
    const int*   y          = (const int*)d_in[2];
    const int*   y_lens     = (const int*)d_in[3];
    float* out = (float*)d_out;
    float* ws  = (float*)d_ws;

    const int npairs = (BATCH * TMAX * U1) / 2;           // 133120 waves
    const int grid = (npairs + 15) / 16;                  // 16 waves/block
    lse_kernel<<<grid, 1024, 0, stream>>>(logits, y, logit_lens, y_lens, ws);
    alpha_kernel<<<BATCH, 64, 0, stream>>>(ws, logit_lens, y_lens, ws + LOSS_OFF);
    finalize_kernel<<<1, 64, 0, stream>>>(ws + LOSS_OFF, out);
}